// Round 1
// baseline (504.029 us; speedup 1.0000x reference)
//
#include <hip/hip_runtime.h>
#include <hip/hip_bf16.h>
#include <math.h>

#define N_EMBD 1024
#define N_HEADC 16
#define HEAD_D 64

typedef __attribute__((ext_vector_type(8))) short short8;
typedef __attribute__((ext_vector_type(4))) float floatx4;

__device__ __forceinline__ ushort f2b(float f) {
    __hip_bfloat16 h = __float2bfloat16(f);
    return *reinterpret_cast<ushort*>(&h);
}

__device__ __forceinline__ void async_cp16(const void* gsrc, void* ldst) {
    __builtin_amdgcn_global_load_lds(
        (const __attribute__((address_space(1))) void*)gsrc,
        (__attribute__((address_space(3))) void*)ldst, 16, 0, 0);
}

// Bijective XCD-chunk swizzle (m204 form): dispatch ids congruent mod 8 get a
// contiguous chunk of tile ids -> same-panel tiles share one XCD L2.
__device__ __forceinline__ int xcd_swizzle(int bid, int nwg) {
    const int q = nwg >> 3, r = nwg & 7;
    const int xcd = bid & 7, loc = bid >> 3;
    return (xcd < r ? xcd * (q + 1) : r * (q + 1) + (xcd - r) * q) + loc;
}

// ---------------------------------------------------------------------------
// LayerNorm: fp32 in, bf16 out. One block (256 thr) per row of C=1024.
// Vectorized: one float4 per thread (G13).
// ---------------------------------------------------------------------------
__global__ __launch_bounds__(256) void ln_kernel(const float* __restrict__ x,
                                                 const float* __restrict__ w,
                                                 const float* __restrict__ b,
                                                 ushort* __restrict__ out) {
    const int row = blockIdx.x;
    const int t = threadIdx.x;
    const float4 v = reinterpret_cast<const float4*>(x + (size_t)row * N_EMBD)[t];
    float s  = v.x + v.y + v.z + v.w;
    float ss = v.x * v.x + v.y * v.y + v.z * v.z + v.w * v.w;
    for (int o = 32; o > 0; o >>= 1) {
        s  += __shfl_down(s, o);
        ss += __shfl_down(ss, o);
    }
    __shared__ float as_[4], ass_[4];
    const int wid = t >> 6, lane = t & 63;
    if (lane == 0) { as_[wid] = s; ass_[wid] = ss; }
    __syncthreads();
    const float ts  = as_[0] + as_[1] + as_[2] + as_[3];
    const float tss = ass_[0] + ass_[1] + ass_[2] + ass_[3];
    const float mu  = ts * (1.f / N_EMBD);
    const float var = tss * (1.f / N_EMBD) - mu * mu;
    const float inv = rsqrtf(var + 1e-5f);
    const float4 wv = reinterpret_cast<const float4*>(w)[t];
    const float4 bv = reinterpret_cast<const float4*>(b)[t];
    ushort4 o;
    o.x = f2b((v.x - mu) * inv * wv.x + bv.x);
    o.y = f2b((v.y - mu) * inv * wv.y + bv.y);
    o.z = f2b((v.z - mu) * inv * wv.z + bv.z);
    o.w = f2b((v.w - mu) * inv * wv.w + bv.w);
    reinterpret_cast<ushort4*>(out + (size_t)row * N_EMBD)[t] = o;
}

// ---------------------------------------------------------------------------
// Transpose + convert: W[K,N] fp32 -> Wt[N,K] bf16. 32x32 tiles, 256 thr.
// ---------------------------------------------------------------------------
__global__ void convtrans_kernel(const float* __restrict__ W,
                                 ushort* __restrict__ Wt, int K, int N) {
    __shared__ float tile[32][33];
    const int tid = threadIdx.x;
    const int r = tid >> 3;
    const int c4 = (tid & 7) * 4;
    const int bx = blockIdx.x, by = blockIdx.y;

    float4 v = *(const float4*)&W[((size_t)(by * 32 + r)) * N + bx * 32 + c4];
    tile[r][c4 + 0] = v.x; tile[r][c4 + 1] = v.y;
    tile[r][c4 + 2] = v.z; tile[r][c4 + 3] = v.w;
    __syncthreads();

    ushort4 u;
    u.x = f2b(tile[c4 + 0][r]); u.y = f2b(tile[c4 + 1][r]);
    u.z = f2b(tile[c4 + 2][r]); u.w = f2b(tile[c4 + 3][r]);
    *(ushort4*)&Wt[((size_t)(bx * 32 + r)) * K + by * 32 + c4] = u;
}

// ---------------------------------------------------------------------------
// bf16 MFMA GEMM (m97 structure) + T1 XCD swizzle.
// ---------------------------------------------------------------------------
__global__ __launch_bounds__(256) void gemm_bf16_kernel(
        const ushort* __restrict__ A,
        const ushort* __restrict__ Bt,
        const float* __restrict__ bias,
        const float* __restrict__ residual,
        float* __restrict__ out32,
        ushort* __restrict__ out16,
        int M, int N, int K, int do_gelu) {
    __shared__ ushort As[128 * 32];
    __shared__ ushort Bs[128 * 32];

    const int tid  = threadIdx.x;
    const int w    = tid >> 6;
    const int lane = tid & 63;
    const int quad = lane >> 4;
    const int l16  = lane & 15;
    const int wm   = w >> 1;
    const int wn   = w & 1;

    int bid = blockIdx.y * gridDim.x + blockIdx.x;
    bid = xcd_swizzle(bid, gridDim.x * gridDim.y);
    const int bx = bid % gridDim.x;
    const int by = bid / gridDim.x;
    const int m0 = by * 128;
    const int n0 = bx * 128;

    floatx4 acc[4][4];
#pragma unroll
    for (int i = 0; i < 4; i++)
#pragma unroll
        for (int j = 0; j < 4; j++) acc[i][j] = (floatx4){0.f, 0.f, 0.f, 0.f};

    for (int k0 = 0; k0 < K; k0 += 32) {
#pragma unroll
        for (int l = 0; l < 2; l++) {
            const int cbase = w * 128 + l * 64;
            const int c = cbase + lane;
            const int row = c >> 2, kc8 = (c & 3) * 8;
            async_cp16(A  + (size_t)(m0 + row) * K + k0 + kc8, &As[cbase * 8]);
            async_cp16(Bt + (size_t)(n0 + row) * K + k0 + kc8, &Bs[cbase * 8]);
        }
        __syncthreads();

        short8 a[4], bf[4];
#pragma unroll
        for (int i = 0; i < 4; i++)
            a[i] = *(const short8*)&As[(wm * 64 + i * 16 + l16) * 32 + quad * 8];
#pragma unroll
        for (int j = 0; j < 4; j++)
            bf[j] = *(const short8*)&Bs[(wn * 64 + j * 16 + l16) * 32 + quad * 8];
#pragma unroll
        for (int i = 0; i < 4; i++)
#pragma unroll
            for (int j = 0; j < 4; j++)
                acc[i][j] = __builtin_amdgcn_mfma_f32_16x16x32_bf16(
                    a[i], bf[j], acc[i][j], 0, 0, 0);
        __syncthreads();
    }

#pragma unroll
    for (int i = 0; i < 4; i++) {
#pragma unroll
        for (int j = 0; j < 4; j++) {
            const int nn = n0 + wn * 64 + j * 16 + l16;
            const float bv = bias[nn];
#pragma unroll
            for (int r = 0; r < 4; r++) {
                const int mm = m0 + wm * 64 + i * 16 + quad * 4 + r;
                float v = acc[i][j][r] + bv;
                if (do_gelu) v = 0.5f * v * (1.f + erff(v * 0.70710678118654752f));
                if (residual) v += residual[(size_t)mm * N + nn];
                if (out32) out32[(size_t)mm * N + nn] = v;
                if (out16) out16[(size_t)mm * N + nn] = f2b(v);
            }
        }
    }
}

// ---------------------------------------------------------------------------
// Flash ALiBi attention, triangle-paired: block handles q-tiles p and 31-p
// (uniform 33 tile-computes/block). One K/V staging shared by both q-tiles.
// exp2-domain softmax; mask only on diagonal tiles; Q frags hoisted.
// ---------------------------------------------------------------------------
#define AT_PAD 72
#define LOG2E 1.4426950408889634f

__device__ __forceinline__ void attn_tile_step(
        short8 aq0, short8 aq1,
        ushort (*__restrict__ Ks)[AT_PAD],
        ushort (*__restrict__ Vt)[AT_PAD],
        ushort (*__restrict__ Ps)[AT_PAD],
        float* m_r, float* l_r, floatx4* acc,
        int q0, int kt, bool domask,
        float qs2, float slope2, const float* skb,
        int w, int quad, int l16) {
    // ---- scores: S[16q x 64k] for this wave ----
    floatx4 sfrag[4];
#pragma unroll
    for (int kb = 0; kb < 4; kb++) {
        const int kcol = kb * 16 + l16;
        short8 bk0 = *(const short8*)&Ks[kcol][quad * 8];
        short8 bk1 = *(const short8*)&Ks[kcol][32 + quad * 8];
        floatx4 s = (floatx4){0.f, 0.f, 0.f, 0.f};
        s = __builtin_amdgcn_mfma_f32_16x16x32_bf16(aq0, bk0, s, 0, 0, 0);
        s = __builtin_amdgcn_mfma_f32_16x16x32_bf16(aq1, bk1, s, 0, 0, 0);
        sfrag[kb] = s;
    }

    // ---- ALiBi + (diagonal-only) mask + online softmax, exp2 domain ----
    const float ktb = (float)(kt * 64);
#pragma unroll
    for (int r = 0; r < 4; r++) {
        const int q = q0 + w * 16 + quad * 4 + r;
        const float rowc = slope2 * ((float)q - ktb);
        float sv[4];
        float rm = -INFINITY;
#pragma unroll
        for (int kb = 0; kb < 4; kb++) {
            float s = fmaf(sfrag[kb][r], qs2, rowc) - skb[kb];
            if (domask) {
                const int k = kt * 64 + kb * 16 + l16;
                s = (k <= q) ? s : -INFINITY;
            }
            sv[kb] = s;
            rm = fmaxf(rm, s);
        }
#pragma unroll
        for (int o = 8; o >= 1; o >>= 1) rm = fmaxf(rm, __shfl_xor(rm, o));
        const float mnew = fmaxf(m_r[r], rm);
        const float corr = exp2f(m_r[r] - mnew);
        float rs = 0.f;
#pragma unroll
        for (int kb = 0; kb < 4; kb++) {
            const float pv = exp2f(sv[kb] - mnew);
            rs += pv;
            Ps[w * 16 + quad * 4 + r][kb * 16 + l16] = f2b(pv);
        }
#pragma unroll
        for (int o = 8; o >= 1; o >>= 1) rs += __shfl_xor(rs, o);
        l_r[r] = l_r[r] * corr + rs;
        m_r[r] = mnew;
#pragma unroll
        for (int db = 0; db < 4; db++) acc[db][r] *= corr;
    }

    // ---- PV (Ps rows are wave-private: no barrier needed) ----
    short8 ap0 = *(const short8*)&Ps[w * 16 + l16][quad * 8];
    short8 ap1 = *(const short8*)&Ps[w * 16 + l16][32 + quad * 8];
#pragma unroll
    for (int db = 0; db < 4; db++) {
        short8 bv0 = *(const short8*)&Vt[db * 16 + l16][quad * 8];
        short8 bv1 = *(const short8*)&Vt[db * 16 + l16][32 + quad * 8];
        acc[db] = __builtin_amdgcn_mfma_f32_16x16x32_bf16(ap0, bv0, acc[db], 0, 0, 0);
        acc[db] = __builtin_amdgcn_mfma_f32_16x16x32_bf16(ap1, bv1, acc[db], 0, 0, 0);
    }
}

__global__ __launch_bounds__(256) void attn_mfma_kernel(
        const ushort* __restrict__ qkv, ushort* __restrict__ y, int B, int T) {
    const int C3 = 3 * N_EMBD;
    const int NT = T / 64;                 // 32

    // XCD swizzle over the full 3D grid: consecutive chunks (same-head blocks,
    // which share K/V) land on the same XCD L2.
    const int gx = gridDim.x, gxy = gridDim.x * gridDim.y;
    int lin = blockIdx.z * gxy + blockIdx.y * gx + blockIdx.x;
    lin = xcd_swizzle(lin, gxy * gridDim.z);
    const int p = lin % gx;                // 0..NT/2-1
    const int h = (lin / gx) % gridDim.y;
    const int b = lin / gxy;

    const int qtA = NT - 1 - p;            // big tile
    const int qtB = p;                     // small tile
    const int tid  = threadIdx.x;
    const int lane = tid & 63;
    const int w    = tid >> 6;
    const int quad = lane >> 4;
    const int l16  = lane & 15;

    __shared__ ushort QsA[64][AT_PAD];
    __shared__ ushort QsB[64][AT_PAD];
    __shared__ ushort Ks[64][AT_PAD];
    __shared__ ushort Vt[64][AT_PAD];
    __shared__ ushort Ps[64][AT_PAD];

    const float slope  = exp2f(-0.5f * (float)(h + 1));
    const float slope2 = slope * LOG2E;
    const float qs2    = 0.125f * LOG2E;
    float skb[4];
#pragma unroll
    for (int kb = 0; kb < 4; kb++) skb[kb] = slope2 * (float)(kb * 16 + l16);

    const int q0A = qtA * 64, q0B = qtB * 64;
    const size_t hb = (size_t)b * T * C3 + (size_t)h * HEAD_D;

    // stage both Q tiles
#pragma unroll
    for (int i = 0; i < 4; i++) {
        int idx = tid + i * 256;
        int row = idx >> 4, d0 = (idx & 15) * 4;
        *(ushort4*)&QsA[row][d0] =
            *(const ushort4*)&qkv[hb + (size_t)(q0A + row) * C3 + d0];
        *(ushort4*)&QsB[row][d0] =
            *(const ushort4*)&qkv[hb + (size_t)(q0B + row) * C3 + d0];
    }
    __syncthreads();

    // hoist Q fragments (constant across kt)
    const int mrow = w * 16 + l16;
    short8 aqA0 = *(const short8*)&QsA[mrow][quad * 8];
    short8 aqA1 = *(const short8*)&QsA[mrow][32 + quad * 8];
    short8 aqB0 = *(const short8*)&QsB[mrow][quad * 8];
    short8 aqB1 = *(const short8*)&QsB[mrow][32 + quad * 8];

    float mA[4], lA[4], mB[4], lB[4];
    floatx4 accA[4], accB[4];
#pragma unroll
    for (int r = 0; r < 4; r++) {
        mA[r] = -INFINITY; lA[r] = 0.f;
        mB[r] = -INFINITY; lB[r] = 0.f;
        accA[r] = (floatx4){0.f, 0.f, 0.f, 0.f};
        accB[r] = (floatx4){0.f, 0.f, 0.f, 0.f};
    }

    for (int kt = 0; kt <= qtA; kt++) {
        // ---- stage K (row-major) and V (transposed), shared by both tiles ----
#pragma unroll
        for (int i = 0; i < 4; i++) {
            int idx = tid + i * 256;
            int row = idx >> 4, d0 = (idx & 15) * 4;
            const size_t src = hb + (size_t)(kt * 64 + row) * C3 + d0;
            *(ushort4*)&Ks[row][d0] = *(const ushort4*)&qkv[src + N_EMBD];
            ushort4 vv = *(const ushort4*)&qkv[src + 2 * N_EMBD];
            Vt[d0 + 0][row] = vv.x;
            Vt[d0 + 1][row] = vv.y;
            Vt[d0 + 2][row] = vv.z;
            Vt[d0 + 3][row] = vv.w;
        }
        __syncthreads();

        attn_tile_step(aqA0, aqA1, Ks, Vt, Ps, mA, lA, accA,
                       q0A, kt, kt == qtA, qs2, slope2, skb, w, quad, l16);
        if (kt <= qtB)
            attn_tile_step(aqB0, aqB1, Ks, Vt, Ps, mB, lB, accB,
                           q0B, kt, kt == qtB, qs2, slope2, skb, w, quad, l16);
        __syncthreads();
    }

    // ---- epilogue ----
#pragma unroll
    for (int r = 0; r < 4; r++) {
        const int qa = q0A + w * 16 + quad * 4 + r;
        const int qb = q0B + w * 16 + quad * 4 + r;
        const float ia = 1.f / lA[r];
        const float ib = 1.f / lB[r];
#pragma unroll
        for (int db = 0; db < 4; db++) {
            y[((size_t)b * T + qa) * N_EMBD + h * HEAD_D + db * 16 + l16] =
                f2b(accA[db][r] * ia);
            y[((size_t)b * T + qb) * N_EMBD + h * HEAD_D + db * 16 + l16] =
                f2b(accB[db][r] * ib);
        }
    }
}

// ---------------------------------------------------------------------------
extern "C" void kernel_launch(void* const* d_in, const int* in_sizes, int n_in,
                              void* d_out, int out_size, void* d_ws, size_t ws_size,
                              hipStream_t stream) {
    const int B = 2, T = 2048, C = N_EMBD;
    const int M = B * T;

    const float* x      = (const float*)d_in[0];
    const float* ln1_w  = (const float*)d_in[1];
    const float* ln1_b  = (const float*)d_in[2];
    const float* w_qkv  = (const float*)d_in[3];
    const float* b_qkv  = (const float*)d_in[4];
    const float* w_proj = (const float*)d_in[5];
    const float* b_proj = (const float*)d_in[6];
    const float* ln2_w  = (const float*)d_in[7];
    const float* ln2_b  = (const float*)d_in[8];
    const float* w_fc   = (const float*)d_in[9];
    const float* b_fc   = (const float*)d_in[10];
    const float* w_fc2  = (const float*)d_in[11];
    const float* b_fc2  = (const float*)d_in[12];
    float* out = (float*)d_out;

    char* ws = (char*)d_ws;
    size_t off = 0;
    ushort* wt_qkv  = (ushort*)(ws + off); off += (size_t)3 * C * C * 2;
    ushort* wt_proj = (ushort*)(ws + off); off += (size_t)C * C * 2;
    ushort* wt_fc   = (ushort*)(ws + off); off += (size_t)4 * C * C * 2;
    ushort* wt_fc2  = (ushort*)(ws + off); off += (size_t)4 * C * C * 2;
    ushort* h16     = (ushort*)(ws + off); off += (size_t)M * C * 2;
    ushort* qkv16   = (ushort*)(ws + off); off += (size_t)M * 3 * C * 2;
    ushort* y16     = (ushort*)(ws + off); off += (size_t)M * C * 2;
    ushort* fc16    = (ushort*)(ws + off); off += (size_t)M * 4 * C * 2;

    // 0. weight transpose+convert
    convtrans_kernel<<<dim3(3 * C / 32, C / 32), 256, 0, stream>>>(w_qkv, wt_qkv, C, 3 * C);
    convtrans_kernel<<<dim3(C / 32, C / 32), 256, 0, stream>>>(w_proj, wt_proj, C, C);
    convtrans_kernel<<<dim3(4 * C / 32, C / 32), 256, 0, stream>>>(w_fc, wt_fc, C, 4 * C);
    convtrans_kernel<<<dim3(C / 32, 4 * C / 32), 256, 0, stream>>>(w_fc2, wt_fc2, 4 * C, C);

    // 1. h = LN1(x) -> bf16
    ln_kernel<<<M, 256, 0, stream>>>(x, ln1_w, ln1_b, h16);

    // 2. qkv = h @ w_qkv + b_qkv -> bf16
    gemm_bf16_kernel<<<dim3(3 * C / 128, M / 128), 256, 0, stream>>>(
        h16, wt_qkv, b_qkv, nullptr, nullptr, qkv16, M, 3 * C, C, 0);

    // 3. y = flash ALiBi attention (triangle-paired) -> bf16
    attn_mfma_kernel<<<dim3(T / 128, N_HEADC, B), 256, 0, stream>>>(
        qkv16, y16, B, T);

    // 4. x1 = x + y @ w_proj + b_proj -> d_out (fp32)
    gemm_bf16_kernel<<<dim3(C / 128, M / 128), 256, 0, stream>>>(
        y16, wt_proj, b_proj, x, out, nullptr, M, C, C, 0);

    // 5. h = LN2(x1) -> bf16
    ln_kernel<<<M, 256, 0, stream>>>(out, ln2_w, ln2_b, h16);

    // 6. fc = gelu(h @ w_fc + b_fc) -> bf16
    gemm_bf16_kernel<<<dim3(4 * C / 128, M / 128), 256, 0, stream>>>(
        h16, wt_fc, b_fc, nullptr, nullptr, fc16, M, 4 * C, C, 1);

    // 7. out = x1 + fc @ w_fc2 + b_fc2 -> d_out (fp32)
    gemm_bf16_kernel<<<dim3(C / 128, M / 128), 256, 0, stream>>>(
        fc16, wt_fc2, b_fc2, out, out, nullptr, M, C, 4 * C, 0);
}

// Round 2
// 482.803 us; speedup vs baseline: 1.0440x; 1.0440x over previous
//
#include <hip/hip_runtime.h>
#include <hip/hip_bf16.h>
#include <math.h>

#define N_EMBD 1024
#define N_HEADC 16
#define HEAD_D 64

typedef __attribute__((ext_vector_type(8))) short short8;
typedef __attribute__((ext_vector_type(4))) float floatx4;

__device__ __forceinline__ ushort f2b(float f) {
    __hip_bfloat16 h = __float2bfloat16(f);
    return *reinterpret_cast<ushort*>(&h);
}

__device__ __forceinline__ void async_cp16(const void* gsrc, void* ldst) {
    __builtin_amdgcn_global_load_lds(
        (const __attribute__((address_space(1))) void*)gsrc,
        (__attribute__((address_space(3))) void*)ldst, 16, 0, 0);
}

// Bijective XCD-chunk swizzle (m204 form).
__device__ __forceinline__ int xcd_swizzle(int bid, int nwg) {
    const int q = nwg >> 3, r = nwg & 7;
    const int xcd = bid & 7, loc = bid >> 3;
    return (xcd < r ? xcd * (q + 1) : r * (q + 1) + (xcd - r) * q) + loc;
}

// ---- DPP 16-lane allreduce (VALU pipe, replaces ds_swizzle shuffles) ----
template <int CTRL>
__device__ __forceinline__ float dppf(float x) {
    int r = __builtin_amdgcn_update_dpp(0, __builtin_bit_cast(int, x),
                                        CTRL, 0xF, 0xF, true);
    return __builtin_bit_cast(float, r);
}
__device__ __forceinline__ float redmax16(float x) {
    x = fmaxf(x, dppf<0xB1>(x));   // quad_perm [1,0,3,2]  (xor 1)
    x = fmaxf(x, dppf<0x4E>(x));   // quad_perm [2,3,0,1]  (xor 2)
    x = fmaxf(x, dppf<0x141>(x));  // row_half_mirror      (xor-ish 4)
    x = fmaxf(x, dppf<0x140>(x));  // row_mirror           (xor-ish 8)
    return x;
}
__device__ __forceinline__ float redsum16(float x) {
    x += dppf<0xB1>(x);
    x += dppf<0x4E>(x);
    x += dppf<0x141>(x);
    x += dppf<0x140>(x);
    return x;
}

// ---------------------------------------------------------------------------
// LayerNorm: fp32 in, bf16 out. One block (256 thr) per row of C=1024.
// ---------------------------------------------------------------------------
__global__ __launch_bounds__(256) void ln_kernel(const float* __restrict__ x,
                                                 const float* __restrict__ w,
                                                 const float* __restrict__ b,
                                                 ushort* __restrict__ out) {
    const int row = blockIdx.x;
    const int t = threadIdx.x;
    const float4 v = reinterpret_cast<const float4*>(x + (size_t)row * N_EMBD)[t];
    float s  = v.x + v.y + v.z + v.w;
    float ss = v.x * v.x + v.y * v.y + v.z * v.z + v.w * v.w;
    for (int o = 32; o > 0; o >>= 1) {
        s  += __shfl_down(s, o);
        ss += __shfl_down(ss, o);
    }
    __shared__ float as_[4], ass_[4];
    const int wid = t >> 6, lane = t & 63;
    if (lane == 0) { as_[wid] = s; ass_[wid] = ss; }
    __syncthreads();
    const float ts  = as_[0] + as_[1] + as_[2] + as_[3];
    const float tss = ass_[0] + ass_[1] + ass_[2] + ass_[3];
    const float mu  = ts * (1.f / N_EMBD);
    const float var = tss * (1.f / N_EMBD) - mu * mu;
    const float inv = rsqrtf(var + 1e-5f);
    const float4 wv = reinterpret_cast<const float4*>(w)[t];
    const float4 bv = reinterpret_cast<const float4*>(b)[t];
    ushort4 o;
    o.x = f2b((v.x - mu) * inv * wv.x + bv.x);
    o.y = f2b((v.y - mu) * inv * wv.y + bv.y);
    o.z = f2b((v.z - mu) * inv * wv.z + bv.z);
    o.w = f2b((v.w - mu) * inv * wv.w + bv.w);
    reinterpret_cast<ushort4*>(out + (size_t)row * N_EMBD)[t] = o;
}

// ---------------------------------------------------------------------------
// Transpose + convert: W[K,N] fp32 -> Wt[N,K] bf16. 32x32 tiles, 256 thr.
// ---------------------------------------------------------------------------
__global__ void convtrans_kernel(const float* __restrict__ W,
                                 ushort* __restrict__ Wt, int K, int N) {
    __shared__ float tile[32][33];
    const int tid = threadIdx.x;
    const int r = tid >> 3;
    const int c4 = (tid & 7) * 4;
    const int bx = blockIdx.x, by = blockIdx.y;

    float4 v = *(const float4*)&W[((size_t)(by * 32 + r)) * N + bx * 32 + c4];
    tile[r][c4 + 0] = v.x; tile[r][c4 + 1] = v.y;
    tile[r][c4 + 2] = v.z; tile[r][c4 + 3] = v.w;
    __syncthreads();

    ushort4 u;
    u.x = f2b(tile[c4 + 0][r]); u.y = f2b(tile[c4 + 1][r]);
    u.z = f2b(tile[c4 + 2][r]); u.w = f2b(tile[c4 + 3][r]);
    *(ushort4*)&Wt[((size_t)(bx * 32 + r)) * K + by * 32 + c4] = u;
}

// ---------------------------------------------------------------------------
// bf16 MFMA GEMM (m97 structure) + T1 XCD swizzle.
// ---------------------------------------------------------------------------
__global__ __launch_bounds__(256) void gemm_bf16_kernel(
        const ushort* __restrict__ A,
        const ushort* __restrict__ Bt,
        const float* __restrict__ bias,
        const float* __restrict__ residual,
        float* __restrict__ out32,
        ushort* __restrict__ out16,
        int M, int N, int K, int do_gelu) {
    __shared__ ushort As[128 * 32];
    __shared__ ushort Bs[128 * 32];

    const int tid  = threadIdx.x;
    const int w    = tid >> 6;
    const int lane = tid & 63;
    const int quad = lane >> 4;
    const int l16  = lane & 15;
    const int wm   = w >> 1;
    const int wn   = w & 1;

    int bid = blockIdx.y * gridDim.x + blockIdx.x;
    bid = xcd_swizzle(bid, gridDim.x * gridDim.y);
    const int bx = bid % gridDim.x;
    const int by = bid / gridDim.x;
    const int m0 = by * 128;
    const int n0 = bx * 128;

    floatx4 acc[4][4];
#pragma unroll
    for (int i = 0; i < 4; i++)
#pragma unroll
        for (int j = 0; j < 4; j++) acc[i][j] = (floatx4){0.f, 0.f, 0.f, 0.f};

    for (int k0 = 0; k0 < K; k0 += 32) {
#pragma unroll
        for (int l = 0; l < 2; l++) {
            const int cbase = w * 128 + l * 64;
            const int c = cbase + lane;
            const int row = c >> 2, kc8 = (c & 3) * 8;
            async_cp16(A  + (size_t)(m0 + row) * K + k0 + kc8, &As[cbase * 8]);
            async_cp16(Bt + (size_t)(n0 + row) * K + k0 + kc8, &Bs[cbase * 8]);
        }
        __syncthreads();

        short8 a[4], bf[4];
#pragma unroll
        for (int i = 0; i < 4; i++)
            a[i] = *(const short8*)&As[(wm * 64 + i * 16 + l16) * 32 + quad * 8];
#pragma unroll
        for (int j = 0; j < 4; j++)
            bf[j] = *(const short8*)&Bs[(wn * 64 + j * 16 + l16) * 32 + quad * 8];
#pragma unroll
        for (int i = 0; i < 4; i++)
#pragma unroll
            for (int j = 0; j < 4; j++)
                acc[i][j] = __builtin_amdgcn_mfma_f32_16x16x32_bf16(
                    a[i], bf[j], acc[i][j], 0, 0, 0);
        __syncthreads();
    }

#pragma unroll
    for (int i = 0; i < 4; i++) {
#pragma unroll
        for (int j = 0; j < 4; j++) {
            const int nn = n0 + wn * 64 + j * 16 + l16;
            const float bv = bias[nn];
#pragma unroll
            for (int r = 0; r < 4; r++) {
                const int mm = m0 + wm * 64 + i * 16 + quad * 4 + r;
                float v = acc[i][j][r] + bv;
                if (do_gelu) v = 0.5f * v * (1.f + erff(v * 0.70710678118654752f));
                if (residual) v += residual[(size_t)mm * N + nn];
                if (out32) out32[(size_t)mm * N + nn] = v;
                if (out16) out16[(size_t)mm * N + nn] = f2b(v);
            }
        }
    }
}

// ---------------------------------------------------------------------------
// Flash ALiBi attention. One block per 64-row q-tile (1024 blocks, 4/CU).
// DPP softmax reduces (VALU pipe); XOR-swizzled Vt and Ps (bank-conflict-free);
// defer-max rescale; exp2-domain softmax; diagonal-only masking.
// ---------------------------------------------------------------------------
#define AT_PAD 72
#define LOG2E 1.4426950408889634f

__device__ __forceinline__ void attn_tile_step(
        short8 aq0, short8 aq1,
        ushort (*__restrict__ Ks)[AT_PAD],
        ushort (*__restrict__ Vt)[AT_PAD],
        ushort (*__restrict__ Ps)[AT_PAD],
        float* m_r, float* l_r, floatx4* acc,
        int q0, int kt, bool domask,
        float qs2, float slope2, const float* skb,
        int w, int quad, int l16) {
    // ---- scores: S[16q x 64k] for this wave ----
    floatx4 sfrag[4];
#pragma unroll
    for (int kb = 0; kb < 4; kb++) {
        const int kcol = kb * 16 + l16;
        short8 bk0 = *(const short8*)&Ks[kcol][quad * 8];
        short8 bk1 = *(const short8*)&Ks[kcol][32 + quad * 8];
        floatx4 s = (floatx4){0.f, 0.f, 0.f, 0.f};
        s = __builtin_amdgcn_mfma_f32_16x16x32_bf16(aq0, bk0, s, 0, 0, 0);
        s = __builtin_amdgcn_mfma_f32_16x16x32_bf16(aq1, bk1, s, 0, 0, 0);
        sfrag[kb] = s;
    }

    // Ps write columns: XOR-swizzled in 8-col blocks keyed by (row>>2)&7.
    const int psw = ((w * 4 + quad) & 7) << 3;
    int pcol[4];
#pragma unroll
    for (int kb = 0; kb < 4; kb++) pcol[kb] = (kb * 16 + l16) ^ psw;

    // ---- ALiBi + (diagonal-only) mask + online softmax, exp2 domain ----
    const float ktb = (float)(kt * 64);
#pragma unroll
    for (int r = 0; r < 4; r++) {
        const int q = q0 + w * 16 + quad * 4 + r;
        const float rowc = slope2 * ((float)q - ktb);
        float sv[4];
        float rm = -INFINITY;
#pragma unroll
        for (int kb = 0; kb < 4; kb++) {
            float s = fmaf(sfrag[kb][r], qs2, rowc) - skb[kb];
            if (domask) {
                const int k = kt * 64 + kb * 16 + l16;
                s = (k <= q) ? s : -INFINITY;
            }
            sv[kb] = s;
            rm = fmaxf(rm, s);
        }
        rm = redmax16(rm);
        if (rm > m_r[r]) {          // defer-max: common case skips rescale
            const float corr = exp2f(m_r[r] - rm);
            m_r[r] = rm;
            l_r[r] *= corr;
#pragma unroll
            for (int db = 0; db < 4; db++) acc[db][r] *= corr;
        }
        float rs = 0.f;
#pragma unroll
        for (int kb = 0; kb < 4; kb++) {
            const float pv = exp2f(sv[kb] - m_r[r]);
            rs += pv;
            Ps[w * 16 + quad * 4 + r][pcol[kb]] = f2b(pv);
        }
        rs = redsum16(rs);
        l_r[r] += rs;
    }

    // ---- PV (Ps rows are wave-private: no barrier needed) ----
    const int prw = ((w * 4 + (l16 >> 2)) & 7) << 3;
    short8 ap0 = *(const short8*)&Ps[w * 16 + l16][(quad * 8) ^ prw];
    short8 ap1 = *(const short8*)&Ps[w * 16 + l16][(32 + quad * 8) ^ prw];
#pragma unroll
    for (int db = 0; db < 4; db++) {
        const int dv = db * 16 + l16;
        const int svw = ((db * 4 + (l16 >> 2)) & 7) << 3;
        short8 bv0 = *(const short8*)&Vt[dv][(quad * 8) ^ svw];
        short8 bv1 = *(const short8*)&Vt[dv][(32 + quad * 8) ^ svw];
        acc[db] = __builtin_amdgcn_mfma_f32_16x16x32_bf16(ap0, bv0, acc[db], 0, 0, 0);
        acc[db] = __builtin_amdgcn_mfma_f32_16x16x32_bf16(ap1, bv1, acc[db], 0, 0, 0);
    }
}

__global__ __launch_bounds__(256) void attn_mfma_kernel(
        const ushort* __restrict__ qkv, ushort* __restrict__ y, int B, int T) {
    const int C3 = 3 * N_EMBD;
    const int NT = T / 64;                 // 32

    // XCD swizzle: contiguous chunks (same (b,h), shared K/V) per XCD L2.
    const int gx = gridDim.x, gxy = gridDim.x * gridDim.y;
    int lin = blockIdx.z * gxy + blockIdx.y * gx + blockIdx.x;
    lin = xcd_swizzle(lin, gxy * gridDim.z);
    const int p = lin % gx;
    const int h = (lin / gx) % gridDim.y;
    const int b = lin / gxy;

    const int qt = NT - 1 - p;             // big tiles first in dispatch order
    const int tid  = threadIdx.x;
    const int lane = tid & 63;
    const int w    = tid >> 6;
    const int quad = lane >> 4;
    const int l16  = lane & 15;

    __shared__ ushort Qs[64][AT_PAD];
    __shared__ ushort Ks[64][AT_PAD];
    __shared__ ushort Vt[64][AT_PAD];
    __shared__ ushort Ps[64][AT_PAD];

    const float slope  = exp2f(-0.5f * (float)(h + 1));
    const float slope2 = slope * LOG2E;
    const float qs2    = 0.125f * LOG2E;
    float skb[4];
#pragma unroll
    for (int kb = 0; kb < 4; kb++) skb[kb] = slope2 * (float)(kb * 16 + l16);

    const int q0 = qt * 64;
    const size_t hb = (size_t)b * T * C3 + (size_t)h * HEAD_D;

    // stage Q tile
#pragma unroll
    for (int i = 0; i < 4; i++) {
        int idx = tid + i * 256;
        int row = idx >> 4, d0 = (idx & 15) * 4;
        *(ushort4*)&Qs[row][d0] =
            *(const ushort4*)&qkv[hb + (size_t)(q0 + row) * C3 + d0];
    }
    __syncthreads();

    // hoist Q fragments (constant across kt)
    const int mrow = w * 16 + l16;
    short8 aq0 = *(const short8*)&Qs[mrow][quad * 8];
    short8 aq1 = *(const short8*)&Qs[mrow][32 + quad * 8];

    float m_r[4], l_r[4];
    floatx4 acc[4];
#pragma unroll
    for (int r = 0; r < 4; r++) {
        m_r[r] = -INFINITY; l_r[r] = 0.f;
        acc[r] = (floatx4){0.f, 0.f, 0.f, 0.f};
    }

    for (int kt = 0; kt <= qt; kt++) {
        // ---- stage K (row-major) and V (transposed, XOR-swizzled rows) ----
#pragma unroll
        for (int i = 0; i < 4; i++) {
            int idx = tid + i * 256;
            int row = idx >> 4, d0 = (idx & 15) * 4;
            const size_t src = hb + (size_t)(kt * 64 + row) * C3 + d0;
            *(ushort4*)&Ks[row][d0] = *(const ushort4*)&qkv[src + N_EMBD];
            ushort4 vv = *(const ushort4*)&qkv[src + 2 * N_EMBD];
            const int rs = row ^ ((idx & 7) << 3);   // swizzle key (d>>2)&7
            Vt[d0 + 0][rs] = vv.x;
            Vt[d0 + 1][rs] = vv.y;
            Vt[d0 + 2][rs] = vv.z;
            Vt[d0 + 3][rs] = vv.w;
        }
        __syncthreads();

        attn_tile_step(aq0, aq1, Ks, Vt, Ps, m_r, l_r, acc,
                       q0, kt, kt == qt, qs2, slope2, skb, w, quad, l16);
        __syncthreads();
    }

    // ---- epilogue ----
#pragma unroll
    for (int r = 0; r < 4; r++) {
        const int qa = q0 + w * 16 + quad * 4 + r;
        const float ia = 1.f / l_r[r];
#pragma unroll
        for (int db = 0; db < 4; db++) {
            y[((size_t)b * T + qa) * N_EMBD + h * HEAD_D + db * 16 + l16] =
                f2b(acc[db][r] * ia);
        }
    }
}

// ---------------------------------------------------------------------------
extern "C" void kernel_launch(void* const* d_in, const int* in_sizes, int n_in,
                              void* d_out, int out_size, void* d_ws, size_t ws_size,
                              hipStream_t stream) {
    const int B = 2, T = 2048, C = N_EMBD;
    const int M = B * T;

    const float* x      = (const float*)d_in[0];
    const float* ln1_w  = (const float*)d_in[1];
    const float* ln1_b  = (const float*)d_in[2];
    const float* w_qkv  = (const float*)d_in[3];
    const float* b_qkv  = (const float*)d_in[4];
    const float* w_proj = (const float*)d_in[5];
    const float* b_proj = (const float*)d_in[6];
    const float* ln2_w  = (const float*)d_in[7];
    const float* ln2_b  = (const float*)d_in[8];
    const float* w_fc   = (const float*)d_in[9];
    const float* b_fc   = (const float*)d_in[10];
    const float* w_fc2  = (const float*)d_in[11];
    const float* b_fc2  = (const float*)d_in[12];
    float* out = (float*)d_out;

    char* ws = (char*)d_ws;
    size_t off = 0;
    ushort* wt_qkv  = (ushort*)(ws + off); off += (size_t)3 * C * C * 2;
    ushort* wt_proj = (ushort*)(ws + off); off += (size_t)C * C * 2;
    ushort* wt_fc   = (ushort*)(ws + off); off += (size_t)4 * C * C * 2;
    ushort* wt_fc2  = (ushort*)(ws + off); off += (size_t)4 * C * C * 2;
    ushort* h16     = (ushort*)(ws + off); off += (size_t)M * C * 2;
    ushort* qkv16   = (ushort*)(ws + off); off += (size_t)M * 3 * C * 2;
    ushort* y16     = (ushort*)(ws + off); off += (size_t)M * C * 2;
    ushort* fc16    = (ushort*)(ws + off); off += (size_t)M * 4 * C * 2;

    // 0. weight transpose+convert
    convtrans_kernel<<<dim3(3 * C / 32, C / 32), 256, 0, stream>>>(w_qkv, wt_qkv, C, 3 * C);
    convtrans_kernel<<<dim3(C / 32, C / 32), 256, 0, stream>>>(w_proj, wt_proj, C, C);
    convtrans_kernel<<<dim3(4 * C / 32, C / 32), 256, 0, stream>>>(w_fc, wt_fc, C, 4 * C);
    convtrans_kernel<<<dim3(C / 32, 4 * C / 32), 256, 0, stream>>>(w_fc2, wt_fc2, 4 * C, C);

    // 1. h = LN1(x) -> bf16
    ln_kernel<<<M, 256, 0, stream>>>(x, ln1_w, ln1_b, h16);

    // 2. qkv = h @ w_qkv + b_qkv -> bf16
    gemm_bf16_kernel<<<dim3(3 * C / 128, M / 128), 256, 0, stream>>>(
        h16, wt_qkv, b_qkv, nullptr, nullptr, qkv16, M, 3 * C, C, 0);

    // 3. y = flash ALiBi attention -> bf16
    attn_mfma_kernel<<<dim3(T / 64, N_HEADC, B), 256, 0, stream>>>(
        qkv16, y16, B, T);

    // 4. x1 = x + y @ w_proj + b_proj -> d_out (fp32)
    gemm_bf16_kernel<<<dim3(C / 128, M / 128), 256, 0, stream>>>(
        y16, wt_proj, b_proj, x, out, nullptr, M, C, C, 0);

    // 5. h = LN2(x1) -> bf16
    ln_kernel<<<M, 256, 0, stream>>>(out, ln2_w, ln2_b, h16);

    // 6. fc = gelu(h @ w_fc + b_fc) -> bf16
    gemm_bf16_kernel<<<dim3(4 * C / 128, M / 128), 256, 0, stream>>>(
        h16, wt_fc, b_fc, nullptr, nullptr, fc16, M, 4 * C, C, 1);

    // 7. out = x1 + fc @ w_fc2 + b_fc2 -> d_out (fp32)
    gemm_bf16_kernel<<<dim3(C / 128, M / 128), 256, 0, stream>>>(
        fc16, wt_fc2, b_fc2, out, out, nullptr, M, C, 4 * C, 0);
}

// Round 3
// 466.733 us; speedup vs baseline: 1.0799x; 1.0344x over previous
//
#include <hip/hip_runtime.h>
#include <hip/hip_bf16.h>
#include <math.h>

#define N_EMBD 1024
#define N_HEADC 16
#define HEAD_D 64

typedef __attribute__((ext_vector_type(8))) short short8;
typedef __attribute__((ext_vector_type(4))) float floatx4;

__device__ __forceinline__ ushort f2b(float f) {
    __hip_bfloat16 h = __float2bfloat16(f);
    return *reinterpret_cast<ushort*>(&h);
}

__device__ __forceinline__ void async_cp16(const void* gsrc, void* ldst) {
    __builtin_amdgcn_global_load_lds(
        (const __attribute__((address_space(1))) void*)gsrc,
        (__attribute__((address_space(3))) void*)ldst, 16, 0, 0);
}

// Bijective XCD-chunk swizzle (m204 form).
__device__ __forceinline__ int xcd_swizzle(int bid, int nwg) {
    const int q = nwg >> 3, r = nwg & 7;
    const int xcd = bid & 7, loc = bid >> 3;
    return (xcd < r ? xcd * (q + 1) : r * (q + 1) + (xcd - r) * q) + loc;
}

// ---- DPP 16-lane allreduce (VALU pipe) ----
template <int CTRL>
__device__ __forceinline__ float dppf(float x) {
    int r = __builtin_amdgcn_update_dpp(0, __builtin_bit_cast(int, x),
                                        CTRL, 0xF, 0xF, true);
    return __builtin_bit_cast(float, r);
}
__device__ __forceinline__ float redmax16(float x) {
    x = fmaxf(x, dppf<0xB1>(x));
    x = fmaxf(x, dppf<0x4E>(x));
    x = fmaxf(x, dppf<0x141>(x));
    x = fmaxf(x, dppf<0x140>(x));
    return x;
}
__device__ __forceinline__ float redsum16(float x) {
    x += dppf<0xB1>(x);
    x += dppf<0x4E>(x);
    x += dppf<0x141>(x);
    x += dppf<0x140>(x);
    return x;
}

// ---------------------------------------------------------------------------
// LayerNorm: fp32 in, bf16 out. One block (256 thr) per row of C=1024.
// ---------------------------------------------------------------------------
__global__ __launch_bounds__(256) void ln_kernel(const float* __restrict__ x,
                                                 const float* __restrict__ w,
                                                 const float* __restrict__ b,
                                                 ushort* __restrict__ out) {
    const int row = blockIdx.x;
    const int t = threadIdx.x;
    const float4 v = reinterpret_cast<const float4*>(x + (size_t)row * N_EMBD)[t];
    float s  = v.x + v.y + v.z + v.w;
    float ss = v.x * v.x + v.y * v.y + v.z * v.z + v.w * v.w;
    for (int o = 32; o > 0; o >>= 1) {
        s  += __shfl_down(s, o);
        ss += __shfl_down(ss, o);
    }
    __shared__ float as_[4], ass_[4];
    const int wid = t >> 6, lane = t & 63;
    if (lane == 0) { as_[wid] = s; ass_[wid] = ss; }
    __syncthreads();
    const float ts  = as_[0] + as_[1] + as_[2] + as_[3];
    const float tss = ass_[0] + ass_[1] + ass_[2] + ass_[3];
    const float mu  = ts * (1.f / N_EMBD);
    const float var = tss * (1.f / N_EMBD) - mu * mu;
    const float inv = rsqrtf(var + 1e-5f);
    const float4 wv = reinterpret_cast<const float4*>(w)[t];
    const float4 bv = reinterpret_cast<const float4*>(b)[t];
    ushort4 o;
    o.x = f2b((v.x - mu) * inv * wv.x + bv.x);
    o.y = f2b((v.y - mu) * inv * wv.y + bv.y);
    o.z = f2b((v.z - mu) * inv * wv.z + bv.z);
    o.w = f2b((v.w - mu) * inv * wv.w + bv.w);
    reinterpret_cast<ushort4*>(out + (size_t)row * N_EMBD)[t] = o;
}

// ---------------------------------------------------------------------------
// Transpose + convert: W[K,N] fp32 -> Wt[N,K] bf16. 32x32 tiles, 256 thr.
// ---------------------------------------------------------------------------
__global__ void convtrans_kernel(const float* __restrict__ W,
                                 ushort* __restrict__ Wt, int K, int N) {
    __shared__ float tile[32][33];
    const int tid = threadIdx.x;
    const int r = tid >> 3;
    const int c4 = (tid & 7) * 4;
    const int bx = blockIdx.x, by = blockIdx.y;

    float4 v = *(const float4*)&W[((size_t)(by * 32 + r)) * N + bx * 32 + c4];
    tile[r][c4 + 0] = v.x; tile[r][c4 + 1] = v.y;
    tile[r][c4 + 2] = v.z; tile[r][c4 + 3] = v.w;
    __syncthreads();

    ushort4 u;
    u.x = f2b(tile[c4 + 0][r]); u.y = f2b(tile[c4 + 1][r]);
    u.z = f2b(tile[c4 + 2][r]); u.w = f2b(tile[c4 + 3][r]);
    *(ushort4*)&Wt[((size_t)(bx * 32 + r)) * K + by * 32 + c4] = u;
}

// ---------------------------------------------------------------------------
// bf16 MFMA GEMM: m97 fragment layout + double-buffered LDS (2-phase T3
// minimum recipe: issue next-tile global_load_lds BEFORE compute, single
// barrier per K-step so the implicit vmcnt(0) drain overlaps compute).
// ---------------------------------------------------------------------------
__device__ __forceinline__ void gemm_stage(
        const ushort* __restrict__ A, const ushort* __restrict__ Bt,
        ushort* As, ushort* Bs,
        int m0, int n0, int K, int k0, int w, int lane) {
#pragma unroll
    for (int l = 0; l < 2; l++) {
        const int cbase = w * 128 + l * 64;
        const int c = cbase + lane;
        const int row = c >> 2, kc8 = (c & 3) * 8;
        async_cp16(A  + (size_t)(m0 + row) * K + k0 + kc8, &As[cbase * 8]);
        async_cp16(Bt + (size_t)(n0 + row) * K + k0 + kc8, &Bs[cbase * 8]);
    }
}

__device__ __forceinline__ void gemm_compute(
        const ushort* As, const ushort* Bs, floatx4 (*acc)[4],
        int wm, int wn, int quad, int l16) {
    short8 a[4], bf[4];
#pragma unroll
    for (int i = 0; i < 4; i++)
        a[i] = *(const short8*)&As[(wm * 64 + i * 16 + l16) * 32 + quad * 8];
#pragma unroll
    for (int j = 0; j < 4; j++)
        bf[j] = *(const short8*)&Bs[(wn * 64 + j * 16 + l16) * 32 + quad * 8];
#pragma unroll
    for (int i = 0; i < 4; i++)
#pragma unroll
        for (int j = 0; j < 4; j++)
            acc[i][j] = __builtin_amdgcn_mfma_f32_16x16x32_bf16(
                a[i], bf[j], acc[i][j], 0, 0, 0);
}

__global__ __launch_bounds__(256) void gemm_bf16_kernel(
        const ushort* __restrict__ A,
        const ushort* __restrict__ Bt,
        const float* __restrict__ bias,
        const float* __restrict__ residual,
        float* __restrict__ out32,
        ushort* __restrict__ out16,
        int M, int N, int K, int do_gelu) {
    __shared__ ushort As[2][128 * 32];
    __shared__ ushort Bs[2][128 * 32];

    const int tid  = threadIdx.x;
    const int w    = tid >> 6;
    const int lane = tid & 63;
    const int quad = lane >> 4;
    const int l16  = lane & 15;
    const int wm   = w >> 1;
    const int wn   = w & 1;

    int bid = blockIdx.y * gridDim.x + blockIdx.x;
    bid = xcd_swizzle(bid, gridDim.x * gridDim.y);
    const int bx = bid % gridDim.x;
    const int by = bid / gridDim.x;
    const int m0 = by * 128;
    const int n0 = bx * 128;

    floatx4 acc[4][4];
#pragma unroll
    for (int i = 0; i < 4; i++)
#pragma unroll
        for (int j = 0; j < 4; j++) acc[i][j] = (floatx4){0.f, 0.f, 0.f, 0.f};

    const int nt = K >> 5;   // K-steps of 32; always even here (32 or 128)

    gemm_stage(A, Bt, As[0], Bs[0], m0, n0, K, 0, w, lane);
    __syncthreads();         // implicit vmcnt(0): tile 0 resident

    for (int t = 0; t < nt; t += 2) {
        // phase A: prefetch tile t+1 into buf1, compute tile t from buf0
        gemm_stage(A, Bt, As[1], Bs[1], m0, n0, K, (t + 1) << 5, w, lane);
        gemm_compute(As[0], Bs[0], acc, wm, wn, quad, l16);
        __syncthreads();     // drains vmcnt: buf1 ready
        // phase B: prefetch tile t+2 into buf0, compute tile t+1 from buf1
        if (t + 2 < nt)
            gemm_stage(A, Bt, As[0], Bs[0], m0, n0, K, (t + 2) << 5, w, lane);
        gemm_compute(As[1], Bs[1], acc, wm, wn, quad, l16);
        __syncthreads();     // drains vmcnt: buf0 ready
    }

#pragma unroll
    for (int i = 0; i < 4; i++) {
#pragma unroll
        for (int j = 0; j < 4; j++) {
            const int nn = n0 + wn * 64 + j * 16 + l16;
            const float bv = bias[nn];
#pragma unroll
            for (int r = 0; r < 4; r++) {
                const int mm = m0 + wm * 64 + i * 16 + quad * 4 + r;
                float v = acc[i][j][r] + bv;
                if (do_gelu) v = 0.5f * v * (1.f + erff(v * 0.70710678118654752f));
                if (residual) v += residual[(size_t)mm * N + nn];
                if (out32) out32[(size_t)mm * N + nn] = v;
                if (out16) out16[(size_t)mm * N + nn] = f2b(v);
            }
        }
    }
}

// ---------------------------------------------------------------------------
// Flash ALiBi attention (unchanged from R2: DPP reduces, XOR-swizzled Vt/Ps,
// defer-max, 1024 blocks).
// ---------------------------------------------------------------------------
#define AT_PAD 72
#define LOG2E 1.4426950408889634f

__device__ __forceinline__ void attn_tile_step(
        short8 aq0, short8 aq1,
        ushort (*__restrict__ Ks)[AT_PAD],
        ushort (*__restrict__ Vt)[AT_PAD],
        ushort (*__restrict__ Ps)[AT_PAD],
        float* m_r, float* l_r, floatx4* acc,
        int q0, int kt, bool domask,
        float qs2, float slope2, const float* skb,
        int w, int quad, int l16) {
    floatx4 sfrag[4];
#pragma unroll
    for (int kb = 0; kb < 4; kb++) {
        const int kcol = kb * 16 + l16;
        short8 bk0 = *(const short8*)&Ks[kcol][quad * 8];
        short8 bk1 = *(const short8*)&Ks[kcol][32 + quad * 8];
        floatx4 s = (floatx4){0.f, 0.f, 0.f, 0.f};
        s = __builtin_amdgcn_mfma_f32_16x16x32_bf16(aq0, bk0, s, 0, 0, 0);
        s = __builtin_amdgcn_mfma_f32_16x16x32_bf16(aq1, bk1, s, 0, 0, 0);
        sfrag[kb] = s;
    }

    const int psw = ((w * 4 + quad) & 7) << 3;
    int pcol[4];
#pragma unroll
    for (int kb = 0; kb < 4; kb++) pcol[kb] = (kb * 16 + l16) ^ psw;

    const float ktb = (float)(kt * 64);
#pragma unroll
    for (int r = 0; r < 4; r++) {
        const int q = q0 + w * 16 + quad * 4 + r;
        const float rowc = slope2 * ((float)q - ktb);
        float sv[4];
        float rm = -INFINITY;
#pragma unroll
        for (int kb = 0; kb < 4; kb++) {
            float s = fmaf(sfrag[kb][r], qs2, rowc) - skb[kb];
            if (domask) {
                const int k = kt * 64 + kb * 16 + l16;
                s = (k <= q) ? s : -INFINITY;
            }
            sv[kb] = s;
            rm = fmaxf(rm, s);
        }
        rm = redmax16(rm);
        if (rm > m_r[r]) {
            const float corr = exp2f(m_r[r] - rm);
            m_r[r] = rm;
            l_r[r] *= corr;
#pragma unroll
            for (int db = 0; db < 4; db++) acc[db][r] *= corr;
        }
        float rs = 0.f;
#pragma unroll
        for (int kb = 0; kb < 4; kb++) {
            const float pv = exp2f(sv[kb] - m_r[r]);
            rs += pv;
            Ps[w * 16 + quad * 4 + r][pcol[kb]] = f2b(pv);
        }
        rs = redsum16(rs);
        l_r[r] += rs;
    }

    const int prw = ((w * 4 + (l16 >> 2)) & 7) << 3;
    short8 ap0 = *(const short8*)&Ps[w * 16 + l16][(quad * 8) ^ prw];
    short8 ap1 = *(const short8*)&Ps[w * 16 + l16][(32 + quad * 8) ^ prw];
#pragma unroll
    for (int db = 0; db < 4; db++) {
        const int dv = db * 16 + l16;
        const int svw = ((db * 4 + (l16 >> 2)) & 7) << 3;
        short8 bv0 = *(const short8*)&Vt[dv][(quad * 8) ^ svw];
        short8 bv1 = *(const short8*)&Vt[dv][(32 + quad * 8) ^ svw];
        acc[db] = __builtin_amdgcn_mfma_f32_16x16x32_bf16(ap0, bv0, acc[db], 0, 0, 0);
        acc[db] = __builtin_amdgcn_mfma_f32_16x16x32_bf16(ap1, bv1, acc[db], 0, 0, 0);
    }
}

__global__ __launch_bounds__(256) void attn_mfma_kernel(
        const ushort* __restrict__ qkv, ushort* __restrict__ y, int B, int T) {
    const int C3 = 3 * N_EMBD;
    const int NT = T / 64;

    const int gx = gridDim.x, gxy = gridDim.x * gridDim.y;
    int lin = blockIdx.z * gxy + blockIdx.y * gx + blockIdx.x;
    lin = xcd_swizzle(lin, gxy * gridDim.z);
    const int p = lin % gx;
    const int h = (lin / gx) % gridDim.y;
    const int b = lin / gxy;

    const int qt = NT - 1 - p;
    const int tid  = threadIdx.x;
    const int lane = tid & 63;
    const int w    = tid >> 6;
    const int quad = lane >> 4;
    const int l16  = lane & 15;

    __shared__ ushort Qs[64][AT_PAD];
    __shared__ ushort Ks[64][AT_PAD];
    __shared__ ushort Vt[64][AT_PAD];
    __shared__ ushort Ps[64][AT_PAD];

    const float slope  = exp2f(-0.5f * (float)(h + 1));
    const float slope2 = slope * LOG2E;
    const float qs2    = 0.125f * LOG2E;
    float skb[4];
#pragma unroll
    for (int kb = 0; kb < 4; kb++) skb[kb] = slope2 * (float)(kb * 16 + l16);

    const int q0 = qt * 64;
    const size_t hb = (size_t)b * T * C3 + (size_t)h * HEAD_D;

#pragma unroll
    for (int i = 0; i < 4; i++) {
        int idx = tid + i * 256;
        int row = idx >> 4, d0 = (idx & 15) * 4;
        *(ushort4*)&Qs[row][d0] =
            *(const ushort4*)&qkv[hb + (size_t)(q0 + row) * C3 + d0];
    }
    __syncthreads();

    const int mrow = w * 16 + l16;
    short8 aq0 = *(const short8*)&Qs[mrow][quad * 8];
    short8 aq1 = *(const short8*)&Qs[mrow][32 + quad * 8];

    float m_r[4], l_r[4];
    floatx4 acc[4];
#pragma unroll
    for (int r = 0; r < 4; r++) {
        m_r[r] = -INFINITY; l_r[r] = 0.f;
        acc[r] = (floatx4){0.f, 0.f, 0.f, 0.f};
    }

    for (int kt = 0; kt <= qt; kt++) {
#pragma unroll
        for (int i = 0; i < 4; i++) {
            int idx = tid + i * 256;
            int row = idx >> 4, d0 = (idx & 15) * 4;
            const size_t src = hb + (size_t)(kt * 64 + row) * C3 + d0;
            *(ushort4*)&Ks[row][d0] = *(const ushort4*)&qkv[src + N_EMBD];
            ushort4 vv = *(const ushort4*)&qkv[src + 2 * N_EMBD];
            const int rs = row ^ ((idx & 7) << 3);
            Vt[d0 + 0][rs] = vv.x;
            Vt[d0 + 1][rs] = vv.y;
            Vt[d0 + 2][rs] = vv.z;
            Vt[d0 + 3][rs] = vv.w;
        }
        __syncthreads();

        attn_tile_step(aq0, aq1, Ks, Vt, Ps, m_r, l_r, acc,
                       q0, kt, kt == qt, qs2, slope2, skb, w, quad, l16);
        __syncthreads();
    }

#pragma unroll
    for (int r = 0; r < 4; r++) {
        const int qa = q0 + w * 16 + quad * 4 + r;
        const float ia = 1.f / l_r[r];
#pragma unroll
        for (int db = 0; db < 4; db++) {
            y[((size_t)b * T + qa) * N_EMBD + h * HEAD_D + db * 16 + l16] =
                f2b(acc[db][r] * ia);
        }
    }
}

// ---------------------------------------------------------------------------
extern "C" void kernel_launch(void* const* d_in, const int* in_sizes, int n_in,
                              void* d_out, int out_size, void* d_ws, size_t ws_size,
                              hipStream_t stream) {
    const int B = 2, T = 2048, C = N_EMBD;
    const int M = B * T;

    const float* x      = (const float*)d_in[0];
    const float* ln1_w  = (const float*)d_in[1];
    const float* ln1_b  = (const float*)d_in[2];
    const float* w_qkv  = (const float*)d_in[3];
    const float* b_qkv  = (const float*)d_in[4];
    const float* w_proj = (const float*)d_in[5];
    const float* b_proj = (const float*)d_in[6];
    const float* ln2_w  = (const float*)d_in[7];
    const float* ln2_b  = (const float*)d_in[8];
    const float* w_fc   = (const float*)d_in[9];
    const float* b_fc   = (const float*)d_in[10];
    const float* w_fc2  = (const float*)d_in[11];
    const float* b_fc2  = (const float*)d_in[12];
    float* out = (float*)d_out;

    char* ws = (char*)d_ws;
    size_t off = 0;
    ushort* wt_qkv  = (ushort*)(ws + off); off += (size_t)3 * C * C * 2;
    ushort* wt_proj = (ushort*)(ws + off); off += (size_t)C * C * 2;
    ushort* wt_fc   = (ushort*)(ws + off); off += (size_t)4 * C * C * 2;
    ushort* wt_fc2  = (ushort*)(ws + off); off += (size_t)4 * C * C * 2;
    ushort* h16     = (ushort*)(ws + off); off += (size_t)M * C * 2;
    ushort* qkv16   = (ushort*)(ws + off); off += (size_t)M * 3 * C * 2;
    ushort* y16     = (ushort*)(ws + off); off += (size_t)M * C * 2;
    ushort* fc16    = (ushort*)(ws + off); off += (size_t)M * 4 * C * 2;

    // 0. weight transpose+convert
    convtrans_kernel<<<dim3(3 * C / 32, C / 32), 256, 0, stream>>>(w_qkv, wt_qkv, C, 3 * C);
    convtrans_kernel<<<dim3(C / 32, C / 32), 256, 0, stream>>>(w_proj, wt_proj, C, C);
    convtrans_kernel<<<dim3(4 * C / 32, C / 32), 256, 0, stream>>>(w_fc, wt_fc, C, 4 * C);
    convtrans_kernel<<<dim3(C / 32, 4 * C / 32), 256, 0, stream>>>(w_fc2, wt_fc2, 4 * C, C);

    // 1. h = LN1(x) -> bf16
    ln_kernel<<<M, 256, 0, stream>>>(x, ln1_w, ln1_b, h16);

    // 2. qkv = h @ w_qkv + b_qkv -> bf16
    gemm_bf16_kernel<<<dim3(3 * C / 128, M / 128), 256, 0, stream>>>(
        h16, wt_qkv, b_qkv, nullptr, nullptr, qkv16, M, 3 * C, C, 0);

    // 3. y = flash ALiBi attention -> bf16
    attn_mfma_kernel<<<dim3(T / 64, N_HEADC, B), 256, 0, stream>>>(
        qkv16, y16, B, T);

    // 4. x1 = x + y @ w_proj + b_proj -> d_out (fp32)
    gemm_bf16_kernel<<<dim3(C / 128, M / 128), 256, 0, stream>>>(
        y16, wt_proj, b_proj, x, out, nullptr, M, C, C, 0);

    // 5. h = LN2(x1) -> bf16
    ln_kernel<<<M, 256, 0, stream>>>(out, ln2_w, ln2_b, h16);

    // 6. fc = gelu(h @ w_fc + b_fc) -> bf16
    gemm_bf16_kernel<<<dim3(4 * C / 128, M / 128), 256, 0, stream>>>(
        h16, wt_fc, b_fc, nullptr, nullptr, fc16, M, 4 * C, C, 1);

    // 7. out = x1 + fc @ w_fc2 + b_fc2 -> d_out (fp32)
    gemm_bf16_kernel<<<dim3(C / 128, M / 128), 256, 0, stream>>>(
        fc16, wt_fc2, b_fc2, out, out, nullptr, M, C, 4 * C, 0);
}

// Round 4
// 440.885 us; speedup vs baseline: 1.1432x; 1.0586x over previous
//
#include <hip/hip_runtime.h>
#include <hip/hip_bf16.h>
#include <math.h>

#define N_EMBD 1024
#define N_HEADC 16
#define HEAD_D 64

typedef __attribute__((ext_vector_type(8))) short short8;
typedef __attribute__((ext_vector_type(4))) float floatx4;

__device__ __forceinline__ ushort f2b(float f) {
    __hip_bfloat16 h = __float2bfloat16(f);
    return *reinterpret_cast<ushort*>(&h);
}

__device__ __forceinline__ void async_cp16(const void* gsrc, void* ldst) {
    __builtin_amdgcn_global_load_lds(
        (const __attribute__((address_space(1))) void*)gsrc,
        (__attribute__((address_space(3))) void*)ldst, 16, 0, 0);
}

// Bijective XCD-chunk swizzle (m204 form).
__device__ __forceinline__ int xcd_swizzle(int bid, int nwg) {
    const int q = nwg >> 3, r = nwg & 7;
    const int xcd = bid & 7, loc = bid >> 3;
    return (xcd < r ? xcd * (q + 1) : r * (q + 1) + (xcd - r) * q) + loc;
}

// ---- DPP 16-lane allreduce (VALU pipe) ----
template <int CTRL>
__device__ __forceinline__ float dppf(float x) {
    int r = __builtin_amdgcn_update_dpp(0, __builtin_bit_cast(int, x),
                                        CTRL, 0xF, 0xF, true);
    return __builtin_bit_cast(float, r);
}
__device__ __forceinline__ float redmax16(float x) {
    x = fmaxf(x, dppf<0xB1>(x));
    x = fmaxf(x, dppf<0x4E>(x));
    x = fmaxf(x, dppf<0x141>(x));
    x = fmaxf(x, dppf<0x140>(x));
    return x;
}
__device__ __forceinline__ float redsum16(float x) {
    x += dppf<0xB1>(x);
    x += dppf<0x4E>(x);
    x += dppf<0x141>(x);
    x += dppf<0x140>(x);
    return x;
}

// ---------------------------------------------------------------------------
// LayerNorm: fp32 in, bf16 out. One block (256 thr) per row of C=1024.
// ---------------------------------------------------------------------------
__global__ __launch_bounds__(256) void ln_kernel(const float* __restrict__ x,
                                                 const float* __restrict__ w,
                                                 const float* __restrict__ b,
                                                 ushort* __restrict__ out) {
    const int row = blockIdx.x;
    const int t = threadIdx.x;
    const float4 v = reinterpret_cast<const float4*>(x + (size_t)row * N_EMBD)[t];
    float s  = v.x + v.y + v.z + v.w;
    float ss = v.x * v.x + v.y * v.y + v.z * v.z + v.w * v.w;
    for (int o = 32; o > 0; o >>= 1) {
        s  += __shfl_down(s, o);
        ss += __shfl_down(ss, o);
    }
    __shared__ float as_[4], ass_[4];
    const int wid = t >> 6, lane = t & 63;
    if (lane == 0) { as_[wid] = s; ass_[wid] = ss; }
    __syncthreads();
    const float ts  = as_[0] + as_[1] + as_[2] + as_[3];
    const float tss = ass_[0] + ass_[1] + ass_[2] + ass_[3];
    const float mu  = ts * (1.f / N_EMBD);
    const float var = tss * (1.f / N_EMBD) - mu * mu;
    const float inv = rsqrtf(var + 1e-5f);
    const float4 wv = reinterpret_cast<const float4*>(w)[t];
    const float4 bv = reinterpret_cast<const float4*>(b)[t];
    ushort4 o;
    o.x = f2b((v.x - mu) * inv * wv.x + bv.x);
    o.y = f2b((v.y - mu) * inv * wv.y + bv.y);
    o.z = f2b((v.z - mu) * inv * wv.z + bv.z);
    o.w = f2b((v.w - mu) * inv * wv.w + bv.w);
    reinterpret_cast<ushort4*>(out + (size_t)row * N_EMBD)[t] = o;
}

// ---------------------------------------------------------------------------
// Transpose + convert: W[K,N] fp32 -> Wt[N,K] bf16. 32x32 tiles, 256 thr.
// ---------------------------------------------------------------------------
__global__ void convtrans_kernel(const float* __restrict__ W,
                                 ushort* __restrict__ Wt, int K, int N) {
    __shared__ float tile[32][33];
    const int tid = threadIdx.x;
    const int r = tid >> 3;
    const int c4 = (tid & 7) * 4;
    const int bx = blockIdx.x, by = blockIdx.y;

    float4 v = *(const float4*)&W[((size_t)(by * 32 + r)) * N + bx * 32 + c4];
    tile[r][c4 + 0] = v.x; tile[r][c4 + 1] = v.y;
    tile[r][c4 + 2] = v.z; tile[r][c4 + 3] = v.w;
    __syncthreads();

    ushort4 u;
    u.x = f2b(tile[c4 + 0][r]); u.y = f2b(tile[c4 + 1][r]);
    u.z = f2b(tile[c4 + 2][r]); u.w = f2b(tile[c4 + 3][r]);
    *(ushort4*)&Wt[((size_t)(bx * 32 + r)) * K + by * 32 + c4] = u;
}

// ---------------------------------------------------------------------------
// bf16 MFMA GEMM: m97 layout + double-buffered LDS + optional split-K
// (gridDim.z splits K; each z writes an fp32 partial at out32 + z*M*N).
// ---------------------------------------------------------------------------
__device__ __forceinline__ void gemm_stage(
        const ushort* __restrict__ A, const ushort* __restrict__ Bt,
        ushort* As, ushort* Bs,
        int m0, int n0, int K, int k0, int w, int lane) {
#pragma unroll
    for (int l = 0; l < 2; l++) {
        const int cbase = w * 128 + l * 64;
        const int c = cbase + lane;
        const int row = c >> 2, kc8 = (c & 3) * 8;
        async_cp16(A  + (size_t)(m0 + row) * K + k0 + kc8, &As[cbase * 8]);
        async_cp16(Bt + (size_t)(n0 + row) * K + k0 + kc8, &Bs[cbase * 8]);
    }
}

__device__ __forceinline__ void gemm_compute(
        const ushort* As, const ushort* Bs, floatx4 (*acc)[4],
        int wm, int wn, int quad, int l16) {
    short8 a[4], bf[4];
#pragma unroll
    for (int i = 0; i < 4; i++)
        a[i] = *(const short8*)&As[(wm * 64 + i * 16 + l16) * 32 + quad * 8];
#pragma unroll
    for (int j = 0; j < 4; j++)
        bf[j] = *(const short8*)&Bs[(wn * 64 + j * 16 + l16) * 32 + quad * 8];
#pragma unroll
    for (int i = 0; i < 4; i++)
#pragma unroll
        for (int j = 0; j < 4; j++)
            acc[i][j] = __builtin_amdgcn_mfma_f32_16x16x32_bf16(
                a[i], bf[j], acc[i][j], 0, 0, 0);
}

__global__ __launch_bounds__(256) void gemm_bf16_kernel(
        const ushort* __restrict__ A,
        const ushort* __restrict__ Bt,
        const float* __restrict__ bias,
        const float* __restrict__ residual,
        float* __restrict__ out32,
        ushort* __restrict__ out16,
        int M, int N, int K, int do_gelu) {
    __shared__ ushort As[2][128 * 32];
    __shared__ ushort Bs[2][128 * 32];

    const int tid  = threadIdx.x;
    const int w    = tid >> 6;
    const int lane = tid & 63;
    const int quad = lane >> 4;
    const int l16  = lane & 15;
    const int wm   = w >> 1;
    const int wn   = w & 1;

    int bid = blockIdx.y * gridDim.x + blockIdx.x;
    bid = xcd_swizzle(bid, gridDim.x * gridDim.y);
    const int bx = bid % gridDim.x;
    const int by = bid / gridDim.x;
    const int m0 = by * 128;
    const int n0 = bx * 128;

    // split-K: this block covers [kbeg, kbeg+kchunk) and writes partial z
    const int kchunk = K / gridDim.z;
    const int kbeg   = blockIdx.z * kchunk;
    if (gridDim.z > 1)
        out32 += (size_t)blockIdx.z * M * N;

    floatx4 acc[4][4];
#pragma unroll
    for (int i = 0; i < 4; i++)
#pragma unroll
        for (int j = 0; j < 4; j++) acc[i][j] = (floatx4){0.f, 0.f, 0.f, 0.f};

    const int nt = kchunk >> 5;   // K-steps of 32; even for all call sites

    gemm_stage(A, Bt, As[0], Bs[0], m0, n0, K, kbeg, w, lane);
    __syncthreads();

    for (int t = 0; t < nt; t += 2) {
        gemm_stage(A, Bt, As[1], Bs[1], m0, n0, K, kbeg + ((t + 1) << 5), w, lane);
        gemm_compute(As[0], Bs[0], acc, wm, wn, quad, l16);
        __syncthreads();
        if (t + 2 < nt)
            gemm_stage(A, Bt, As[0], Bs[0], m0, n0, K, kbeg + ((t + 2) << 5), w, lane);
        gemm_compute(As[1], Bs[1], acc, wm, wn, quad, l16);
        __syncthreads();
    }

#pragma unroll
    for (int i = 0; i < 4; i++) {
#pragma unroll
        for (int j = 0; j < 4; j++) {
            const int nn = n0 + wn * 64 + j * 16 + l16;
            const float bv = bias ? bias[nn] : 0.f;
#pragma unroll
            for (int r = 0; r < 4; r++) {
                const int mm = m0 + wm * 64 + i * 16 + quad * 4 + r;
                float v = acc[i][j][r] + bv;
                if (do_gelu) v = 0.5f * v * (1.f + erff(v * 0.70710678118654752f));
                if (residual) v += residual[(size_t)mm * N + nn];
                if (out32) out32[(size_t)mm * N + nn] = v;
                if (out16) out16[(size_t)mm * N + nn] = f2b(v);
            }
        }
    }
}

// ---------------------------------------------------------------------------
// Split-K combine: out(x1) += p0 + p1 + bias. One float4 per thread.
// ---------------------------------------------------------------------------
__global__ __launch_bounds__(256) void combine_kernel(
        const float* __restrict__ p0, const float* __restrict__ p1,
        const float* __restrict__ bias, float* __restrict__ out) {
    const int i = blockIdx.x * 256 + threadIdx.x;          // float4 index
    const float4 a = ((const float4*)p0)[i];
    const float4 c = ((const float4*)p1)[i];
    const float4 bb = ((const float4*)bias)[i & 255];      // N=1024 -> 256 f4/row
    float4 o = ((float4*)out)[i];
    o.x += a.x + c.x + bb.x;
    o.y += a.y + c.y + bb.y;
    o.z += a.z + c.z + bb.z;
    o.w += a.w + c.w + bb.w;
    ((float4*)out)[i] = o;
}

// ---------------------------------------------------------------------------
// Flash ALiBi attention (unchanged from R2).
// ---------------------------------------------------------------------------
#define AT_PAD 72
#define LOG2E 1.4426950408889634f

__device__ __forceinline__ void attn_tile_step(
        short8 aq0, short8 aq1,
        ushort (*__restrict__ Ks)[AT_PAD],
        ushort (*__restrict__ Vt)[AT_PAD],
        ushort (*__restrict__ Ps)[AT_PAD],
        float* m_r, float* l_r, floatx4* acc,
        int q0, int kt, bool domask,
        float qs2, float slope2, const float* skb,
        int w, int quad, int l16) {
    floatx4 sfrag[4];
#pragma unroll
    for (int kb = 0; kb < 4; kb++) {
        const int kcol = kb * 16 + l16;
        short8 bk0 = *(const short8*)&Ks[kcol][quad * 8];
        short8 bk1 = *(const short8*)&Ks[kcol][32 + quad * 8];
        floatx4 s = (floatx4){0.f, 0.f, 0.f, 0.f};
        s = __builtin_amdgcn_mfma_f32_16x16x32_bf16(aq0, bk0, s, 0, 0, 0);
        s = __builtin_amdgcn_mfma_f32_16x16x32_bf16(aq1, bk1, s, 0, 0, 0);
        sfrag[kb] = s;
    }

    const int psw = ((w * 4 + quad) & 7) << 3;
    int pcol[4];
#pragma unroll
    for (int kb = 0; kb < 4; kb++) pcol[kb] = (kb * 16 + l16) ^ psw;

    const float ktb = (float)(kt * 64);
#pragma unroll
    for (int r = 0; r < 4; r++) {
        const int q = q0 + w * 16 + quad * 4 + r;
        const float rowc = slope2 * ((float)q - ktb);
        float sv[4];
        float rm = -INFINITY;
#pragma unroll
        for (int kb = 0; kb < 4; kb++) {
            float s = fmaf(sfrag[kb][r], qs2, rowc) - skb[kb];
            if (domask) {
                const int k = kt * 64 + kb * 16 + l16;
                s = (k <= q) ? s : -INFINITY;
            }
            sv[kb] = s;
            rm = fmaxf(rm, s);
        }
        rm = redmax16(rm);
        if (rm > m_r[r]) {
            const float corr = exp2f(m_r[r] - rm);
            m_r[r] = rm;
            l_r[r] *= corr;
#pragma unroll
            for (int db = 0; db < 4; db++) acc[db][r] *= corr;
        }
        float rs = 0.f;
#pragma unroll
        for (int kb = 0; kb < 4; kb++) {
            const float pv = exp2f(sv[kb] - m_r[r]);
            rs += pv;
            Ps[w * 16 + quad * 4 + r][pcol[kb]] = f2b(pv);
        }
        rs = redsum16(rs);
        l_r[r] += rs;
    }

    const int prw = ((w * 4 + (l16 >> 2)) & 7) << 3;
    short8 ap0 = *(const short8*)&Ps[w * 16 + l16][(quad * 8) ^ prw];
    short8 ap1 = *(const short8*)&Ps[w * 16 + l16][(32 + quad * 8) ^ prw];
#pragma unroll
    for (int db = 0; db < 4; db++) {
        const int dv = db * 16 + l16;
        const int svw = ((db * 4 + (l16 >> 2)) & 7) << 3;
        short8 bv0 = *(const short8*)&Vt[dv][(quad * 8) ^ svw];
        short8 bv1 = *(const short8*)&Vt[dv][(32 + quad * 8) ^ svw];
        acc[db] = __builtin_amdgcn_mfma_f32_16x16x32_bf16(ap0, bv0, acc[db], 0, 0, 0);
        acc[db] = __builtin_amdgcn_mfma_f32_16x16x32_bf16(ap1, bv1, acc[db], 0, 0, 0);
    }
}

__global__ __launch_bounds__(256) void attn_mfma_kernel(
        const ushort* __restrict__ qkv, ushort* __restrict__ y, int B, int T) {
    const int C3 = 3 * N_EMBD;
    const int NT = T / 64;

    const int gx = gridDim.x, gxy = gridDim.x * gridDim.y;
    int lin = blockIdx.z * gxy + blockIdx.y * gx + blockIdx.x;
    lin = xcd_swizzle(lin, gxy * gridDim.z);
    const int p = lin % gx;
    const int h = (lin / gx) % gridDim.y;
    const int b = lin / gxy;

    const int qt = NT - 1 - p;
    const int tid  = threadIdx.x;
    const int lane = tid & 63;
    const int w    = tid >> 6;
    const int quad = lane >> 4;
    const int l16  = lane & 15;

    __shared__ ushort Qs[64][AT_PAD];
    __shared__ ushort Ks[64][AT_PAD];
    __shared__ ushort Vt[64][AT_PAD];
    __shared__ ushort Ps[64][AT_PAD];

    const float slope  = exp2f(-0.5f * (float)(h + 1));
    const float slope2 = slope * LOG2E;
    const float qs2    = 0.125f * LOG2E;
    float skb[4];
#pragma unroll
    for (int kb = 0; kb < 4; kb++) skb[kb] = slope2 * (float)(kb * 16 + l16);

    const int q0 = qt * 64;
    const size_t hb = (size_t)b * T * C3 + (size_t)h * HEAD_D;

#pragma unroll
    for (int i = 0; i < 4; i++) {
        int idx = tid + i * 256;
        int row = idx >> 4, d0 = (idx & 15) * 4;
        *(ushort4*)&Qs[row][d0] =
            *(const ushort4*)&qkv[hb + (size_t)(q0 + row) * C3 + d0];
    }
    __syncthreads();

    const int mrow = w * 16 + l16;
    short8 aq0 = *(const short8*)&Qs[mrow][quad * 8];
    short8 aq1 = *(const short8*)&Qs[mrow][32 + quad * 8];

    float m_r[4], l_r[4];
    floatx4 acc[4];
#pragma unroll
    for (int r = 0; r < 4; r++) {
        m_r[r] = -INFINITY; l_r[r] = 0.f;
        acc[r] = (floatx4){0.f, 0.f, 0.f, 0.f};
    }

    for (int kt = 0; kt <= qt; kt++) {
#pragma unroll
        for (int i = 0; i < 4; i++) {
            int idx = tid + i * 256;
            int row = idx >> 4, d0 = (idx & 15) * 4;
            const size_t src = hb + (size_t)(kt * 64 + row) * C3 + d0;
            *(ushort4*)&Ks[row][d0] = *(const ushort4*)&qkv[src + N_EMBD];
            ushort4 vv = *(const ushort4*)&qkv[src + 2 * N_EMBD];
            const int rs = row ^ ((idx & 7) << 3);
            Vt[d0 + 0][rs] = vv.x;
            Vt[d0 + 1][rs] = vv.y;
            Vt[d0 + 2][rs] = vv.z;
            Vt[d0 + 3][rs] = vv.w;
        }
        __syncthreads();

        attn_tile_step(aq0, aq1, Ks, Vt, Ps, m_r, l_r, acc,
                       q0, kt, kt == qt, qs2, slope2, skb, w, quad, l16);
        __syncthreads();
    }

#pragma unroll
    for (int r = 0; r < 4; r++) {
        const int qa = q0 + w * 16 + quad * 4 + r;
        const float ia = 1.f / l_r[r];
#pragma unroll
        for (int db = 0; db < 4; db++) {
            y[((size_t)b * T + qa) * N_EMBD + h * HEAD_D + db * 16 + l16] =
                f2b(acc[db][r] * ia);
        }
    }
}

// ---------------------------------------------------------------------------
extern "C" void kernel_launch(void* const* d_in, const int* in_sizes, int n_in,
                              void* d_out, int out_size, void* d_ws, size_t ws_size,
                              hipStream_t stream) {
    const int B = 2, T = 2048, C = N_EMBD;
    const int M = B * T;

    const float* x      = (const float*)d_in[0];
    const float* ln1_w  = (const float*)d_in[1];
    const float* ln1_b  = (const float*)d_in[2];
    const float* w_qkv  = (const float*)d_in[3];
    const float* b_qkv  = (const float*)d_in[4];
    const float* w_proj = (const float*)d_in[5];
    const float* b_proj = (const float*)d_in[6];
    const float* ln2_w  = (const float*)d_in[7];
    const float* ln2_b  = (const float*)d_in[8];
    const float* w_fc   = (const float*)d_in[9];
    const float* b_fc   = (const float*)d_in[10];
    const float* w_fc2  = (const float*)d_in[11];
    const float* b_fc2  = (const float*)d_in[12];
    float* out = (float*)d_out;

    char* ws = (char*)d_ws;
    size_t off = 0;
    ushort* wt_qkv  = (ushort*)(ws + off); off += (size_t)3 * C * C * 2;
    ushort* wt_proj = (ushort*)(ws + off); off += (size_t)C * C * 2;
    ushort* wt_fc   = (ushort*)(ws + off); off += (size_t)4 * C * C * 2;
    ushort* wt_fc2  = (ushort*)(ws + off); off += (size_t)4 * C * C * 2;
    ushort* h16     = (ushort*)(ws + off); off += (size_t)M * C * 2;
    ushort* qkv16   = (ushort*)(ws + off); off += (size_t)M * 3 * C * 2;
    ushort* y16     = (ushort*)(ws + off); off += (size_t)M * C * 2;
    ushort* fc16    = (ushort*)(ws + off); off += (size_t)M * 4 * C * 2;

    // 0. weight transpose+convert
    convtrans_kernel<<<dim3(3 * C / 32, C / 32), 256, 0, stream>>>(w_qkv, wt_qkv, C, 3 * C);
    convtrans_kernel<<<dim3(C / 32, C / 32), 256, 0, stream>>>(w_proj, wt_proj, C, C);
    convtrans_kernel<<<dim3(4 * C / 32, C / 32), 256, 0, stream>>>(w_fc, wt_fc, C, 4 * C);
    convtrans_kernel<<<dim3(C / 32, 4 * C / 32), 256, 0, stream>>>(w_fc2, wt_fc2, 4 * C, C);

    // 1. h = LN1(x) -> bf16
    ln_kernel<<<M, 256, 0, stream>>>(x, ln1_w, ln1_b, h16);

    // 2. qkv = h @ w_qkv + b_qkv -> bf16
    gemm_bf16_kernel<<<dim3(3 * C / 128, M / 128), 256, 0, stream>>>(
        h16, wt_qkv, b_qkv, nullptr, nullptr, qkv16, M, 3 * C, C, 0);

    // 3. y = flash ALiBi attention -> bf16
    attn_mfma_kernel<<<dim3(T / 64, N_HEADC, B), 256, 0, stream>>>(
        qkv16, y16, B, T);

    // 4. x1 = x + y @ w_proj + b_proj -> d_out (fp32)
    gemm_bf16_kernel<<<dim3(C / 128, M / 128), 256, 0, stream>>>(
        y16, wt_proj, b_proj, x, out, nullptr, M, C, C, 0);

    // 5. h = LN2(x1) -> bf16
    ln_kernel<<<M, 256, 0, stream>>>(out, ln2_w, ln2_b, h16);

    // 6. fc = gelu(h @ w_fc + b_fc) -> bf16
    gemm_bf16_kernel<<<dim3(4 * C / 128, M / 128), 256, 0, stream>>>(
        h16, wt_fc, b_fc, nullptr, nullptr, fc16, M, 4 * C, C, 1);

    // 7. fc2 split-K=2: partials into free ws region (h16..y16 = 40MB, all
    //    dead by now; need 2 * 16MB), then combine out = x1 + p0 + p1 + bias.
    float* part = (float*)h16;
    gemm_bf16_kernel<<<dim3(C / 128, M / 128, 2), 256, 0, stream>>>(
        fc16, wt_fc2, nullptr, nullptr, part, nullptr, M, C, 4 * C, 0);
    combine_kernel<<<(M * C) / (256 * 4), 256, 0, stream>>>(
        part, part + (size_t)M * C, b_fc2, out);
}